// Round 2
// baseline (907.069 us; speedup 1.0000x reference)
//
#include <hip/hip_runtime.h>

typedef __attribute__((ext_vector_type(8))) short bf16x8;
typedef __attribute__((ext_vector_type(4))) float f32x4;

__device__ __forceinline__ float b2f(unsigned short u) {
    union { unsigned int i; float f; } x; x.i = ((unsigned int)u) << 16; return x.f;
}
__device__ __forceinline__ unsigned short f2b(float f) {
    union { float f; unsigned int i; } x; x.f = f;
    unsigned int r = x.i + 0x7fffu + ((x.i >> 16) & 1u);  // RNE
    return (unsigned short)(r >> 16);
}
// f32 -> bf16 hi part, or lo part (residual after hi)
__device__ __forceinline__ unsigned short cvt1(float f, bool lo) {
    unsigned short h = f2b(f);
    if (lo) h = f2b(f - b2f(h));
    return h;
}

// Partial Cox-de Boor exactly as the reference leaves it:
// cols 0-4 degree 3, col 5 degree 2, col 6 degree 1, col 7 degree 0.
// knots = [-1,-1,-1,-1,-0.6,-0.2,0.2,0.6,1,1,1,1]
__device__ __forceinline__ float kan_spline(float t, const float* cpf, float rwf) {
    float c3 = (t >= -1.0f && t < -0.6f) ? 1.0f : 0.0f;
    float c4 = (t >= -0.6f && t < -0.2f) ? 1.0f : 0.0f;
    float c5 = (t >= -0.2f && t <  0.2f) ? 1.0f : 0.0f;
    float c6 = (t >=  0.2f && t <  0.6f) ? 1.0f : 0.0f;
    float c7 = (t >=  0.6f && t <  1.0f) ? 1.0f : 0.0f;
    float d2 = (-0.6f - t) * 2.5f * c3;
    float d3 = (t + 1.0f) * 2.5f * c3 + (-0.2f - t) * 2.5f * c4;
    float d4 = (t + 0.6f) * 2.5f * c4 + ( 0.2f - t) * 2.5f * c5;
    float d5 = (t + 0.2f) * 2.5f * c5 + ( 0.6f - t) * 2.5f * c6;
    float d6 = (t - 0.2f) * 2.5f * c6 + ( 1.0f - t) * 2.5f * c7;
    float e1 = (-0.6f - t) * 2.5f  * d2;
    float e2 = (t + 1.0f) * 2.5f  * d2 + (-0.2f - t) * 1.25f * d3;
    float e3 = (t + 1.0f) * 1.25f * d3 + ( 0.2f - t) * 1.25f * d4;
    float e4 = (t + 0.6f) * 1.25f * d4 + ( 0.6f - t) * 1.25f * d5;
    float e5 = (t + 0.2f) * 1.25f * d5 + ( 1.0f - t) * 1.25f * d6;
    const float r12 = 1.0f / 1.2f;
    float f0 = (-0.6f - t) * 2.5f  * e1;
    float f1 = (t + 1.0f) * 2.5f  * e1 + (-0.2f - t) * 1.25f * e2;
    float f2 = (t + 1.0f) * 1.25f * e2 + ( 0.2f - t) * r12   * e3;
    float f3 = (t + 1.0f) * r12   * e3 + ( 0.6f - t) * r12   * e4;
    float f4 = (t + 0.6f) * r12   * e4 + ( 1.0f - t) * r12   * e5;
    float sp = f0*cpf[0] + f1*cpf[1] + f2*cpf[2] + f3*cpf[3] + f4*cpf[4]
             + e5*cpf[5] + d6*cpf[6] + c7*cpf[7];
    float v = sp * rwf;
    return fminf(fmaxf(v, -10.0f), 10.0f);
}

// per-row mean / rstd of x[1024,2048] f32, fp64 accumulate
__global__ void ln_stats_kernel(const float* __restrict__ x,
                                float* __restrict__ mu, float* __restrict__ rstd) {
    const int row = blockIdx.x;
    const float* p = x + (size_t)row * 2048 + threadIdx.x * 8;
    double s = 0.0, q = 0.0;
#pragma unroll
    for (int i = 0; i < 8; ++i) { float v = p[i]; s += v; q += (double)v * v; }
    for (int o = 32; o > 0; o >>= 1) { s += __shfl_down(s, o, 64); q += __shfl_down(q, o, 64); }
    __shared__ double shs[4], shq[4];
    const int lane = threadIdx.x & 63, w = threadIdx.x >> 6;
    if (lane == 0) { shs[w] = s; shq[w] = q; }
    __syncthreads();
    if (threadIdx.x == 0) {
        double S = shs[0] + shs[1] + shs[2] + shs[3];
        double Q = shq[0] + shq[1] + shq[2] + shq[3];
        double m = S / 2048.0;
        double var = Q / 2048.0 - m * m;
        mu[row] = (float)m;
        rstd[row] = (float)(1.0 / sqrt(var + 1e-5));
    }
}

// S[n] = sum_k W[n,k] (f32 W); one wave per row
__global__ void rowsum_kernel(const float* __restrict__ W,
                              float* __restrict__ S, int K) {
    const int lane = threadIdx.x & 63, w = threadIdx.x >> 6;
    const int row = blockIdx.x * 4 + w;
    const float* p = W + (size_t)row * K;
    double s = 0.0;
    for (int c = lane * 8; c < K; c += 512) {
#pragma unroll
        for (int i = 0; i < 8; ++i) s += p[c + i];
    }
    for (int o = 32; o > 0; o >>= 1) s += __shfl_down(s, o, 64);
    if (lane == 0) S[row] = (float)s;
}

// C[M,N] = A[M,K] @ W[N,K]^T with fused epilogue. W is always f32 (converted
// to bf16 hi/lo during LDS staging).
// EPI 0: A = raw f32 x, 3-phase split GEMM (hi*hi + lo*hi + hi*lo),
//        lin = rstd*(acc - mu*S1) + bias, KAN + NCT, bf16 out
// EPI 1: A = bf16 activations, lin = acc + bias, KAN + NCT, bf16 out
// EPI 2: A = bf16 activations, lin = acc + bias, f32 out
template <int EPI>
__global__ __launch_bounds__(256, 2)
void gemm_kan_kernel(const void* __restrict__ Aptr,
                     const float* __restrict__ W,
                     const float* __restrict__ bias,
                     const float* __restrict__ cp,
                     const float* __restrict__ rw,
                     const float* __restrict__ mu,
                     const float* __restrict__ rstd,
                     const float* __restrict__ S1,
                     void* __restrict__ outp,
                     int M, int N, int K)
{
    __shared__ unsigned short lA[128 * 32];
    __shared__ unsigned short lB[128 * 32];

    const int tid  = threadIdx.x;
    const int lane = tid & 63;
    const int bm = blockIdx.y * 128;
    const int bn = blockIdx.x * 128;
    const int wm = ((tid >> 6) >> 1) * 64;
    const int wn = ((tid >> 6) & 1) * 64;

    f32x4 acc[4][4] = {};
    const int fr = lane & 15;
    const int kg = (lane >> 4) * 8;

    const int NPH = (EPI == 0) ? 3 : 1;
    for (int ph = 0; ph < NPH; ++ph) {
        const bool alo = (ph == 1);   // phase 1: A-lo * B-hi
        const bool blo = (ph == 2);   // phase 2: A-hi * B-lo
        for (int k0 = 0; k0 < K; k0 += 32) {
            // ---- stage B: f32 -> bf16(hi|lo), [128][32] row-major ----
            {
                const int srow = tid >> 1;
                const int scol = (tid & 1) << 4;
                const float* g = W + (size_t)(bn + srow) * K + k0 + scol;
                float4 u0 = ((const float4*)g)[0];
                float4 u1 = ((const float4*)g)[1];
                float4 u2 = ((const float4*)g)[2];
                float4 u3 = ((const float4*)g)[3];
                unsigned short t[16];
                t[0]=cvt1(u0.x,blo); t[1]=cvt1(u0.y,blo); t[2]=cvt1(u0.z,blo); t[3]=cvt1(u0.w,blo);
                t[4]=cvt1(u1.x,blo); t[5]=cvt1(u1.y,blo); t[6]=cvt1(u1.z,blo); t[7]=cvt1(u1.w,blo);
                t[8]=cvt1(u2.x,blo); t[9]=cvt1(u2.y,blo); t[10]=cvt1(u2.z,blo); t[11]=cvt1(u2.w,blo);
                t[12]=cvt1(u3.x,blo); t[13]=cvt1(u3.y,blo); t[14]=cvt1(u3.z,blo); t[15]=cvt1(u3.w,blo);
                unsigned short* d = &lB[srow * 32 + scol];
                ((uint4*)d)[0] = *(const uint4*)&t[0];
                ((uint4*)d)[1] = *(const uint4*)&t[8];
            }
            // ---- stage A ----
            if (EPI == 0) {
                const int srow = tid >> 1;
                const int scol = (tid & 1) << 4;
                const float* g = (const float*)Aptr + (size_t)(bm + srow) * K + k0 + scol;
                float4 u0 = ((const float4*)g)[0];
                float4 u1 = ((const float4*)g)[1];
                float4 u2 = ((const float4*)g)[2];
                float4 u3 = ((const float4*)g)[3];
                unsigned short t[16];
                t[0]=cvt1(u0.x,alo); t[1]=cvt1(u0.y,alo); t[2]=cvt1(u0.z,alo); t[3]=cvt1(u0.w,alo);
                t[4]=cvt1(u1.x,alo); t[5]=cvt1(u1.y,alo); t[6]=cvt1(u1.z,alo); t[7]=cvt1(u1.w,alo);
                t[8]=cvt1(u2.x,alo); t[9]=cvt1(u2.y,alo); t[10]=cvt1(u2.z,alo); t[11]=cvt1(u2.w,alo);
                t[12]=cvt1(u3.x,alo); t[13]=cvt1(u3.y,alo); t[14]=cvt1(u3.z,alo); t[15]=cvt1(u3.w,alo);
                unsigned short* d = &lA[srow * 32 + scol];
                ((uint4*)d)[0] = *(const uint4*)&t[0];
                ((uint4*)d)[1] = *(const uint4*)&t[8];
            } else {
                const unsigned short* Ab = (const unsigned short*)Aptr;
                const int srow = tid >> 2;
                const int sch  = (tid & 3) << 3;
                *(uint4*)&lA[tid * 8] =
                    *(const uint4*)(Ab + (size_t)(bm + srow) * K + k0 + sch);
                *(uint4*)&lA[2048 + tid * 8] =
                    *(const uint4*)(Ab + (size_t)(bm + 64 + srow) * K + k0 + sch);
            }
            __syncthreads();
            bf16x8 aF[4], bF[4];
#pragma unroll
            for (int i = 0; i < 4; ++i)
                aF[i] = *(const bf16x8*)&lA[(wm + i * 16 + fr) * 32 + kg];
#pragma unroll
            for (int j = 0; j < 4; ++j)
                bF[j] = *(const bf16x8*)&lB[(wn + j * 16 + fr) * 32 + kg];
#pragma unroll
            for (int i = 0; i < 4; ++i)
#pragma unroll
                for (int j = 0; j < 4; ++j)
                    acc[i][j] = __builtin_amdgcn_mfma_f32_16x16x32_bf16(aF[i], bF[j], acc[i][j], 0, 0, 0);
            __syncthreads();
        }
    }

    // epilogue: C layout col = lane&15, row = (lane>>4)*4 + reg
    const int rowg = (lane >> 4) * 4;
#pragma unroll
    for (int j = 0; j < 4; ++j) {
        const int n = bn + wn + j * 16 + fr;
        const float bs = bias[n];
        float cpf[8], rwf = 0.0f, s1 = 0.0f;
        if (EPI < 2) {
#pragma unroll
            for (int q = 0; q < 8; ++q) cpf[q] = cp[(size_t)n * 9 + q];
            rwf = rw[n];
        }
        if (EPI == 0) s1 = S1[n];
        const int s = n & 7;  // generator slot: {0,1}->sx, {2,3}->sy, {4..7}->identity
#pragma unroll
        for (int i = 0; i < 4; ++i) {
            const int m0 = bm + wm + i * 16 + rowg;
#pragma unroll
            for (int r = 0; r < 4; ++r) {
                const int m = m0 + r;
                float v = acc[i][j][r];
                if (EPI == 0) v = (v - mu[m] * s1) * rstd[m] + bs;
                else          v += bs;
                if (EPI < 2) {
                    v = kan_spline(tanhf(v), cpf, rwf);
                    float p = __shfl_xor(v, 1, 64);  // partner col n^1 lives in lane^1
                    p = fminf(fmaxf(p, -1.0f), 1.0f);
                    if (s < 4) v += ((s == 2) ? -0.05f : 0.05f) * p;
                }
                if (EPI == 2) ((float*)outp)[(size_t)m * N + n] = v;
                else ((unsigned short*)outp)[(size_t)m * N + n] = f2b(v);
            }
        }
    }
}

extern "C" void kernel_launch(void* const* d_in, const int* in_sizes, int n_in,
                              void* d_out, int out_size, void* d_ws, size_t ws_size,
                              hipStream_t stream) {
    const float* x    = (const float*)d_in[0];
    const float* W1   = (const float*)d_in[1];
    const float* b1   = (const float*)d_in[2];
    const float* cp1  = (const float*)d_in[3];
    const float* rw1  = (const float*)d_in[4];
    const float* W2   = (const float*)d_in[5];
    const float* b2   = (const float*)d_in[6];
    const float* cp2  = (const float*)d_in[7];
    const float* rw2  = (const float*)d_in[8];
    const float* W3   = (const float*)d_in[9];
    const float* b3   = (const float*)d_in[10];
    const float* cp3  = (const float*)d_in[11];
    const float* rw3  = (const float*)d_in[12];
    const float* Wout = (const float*)d_in[13];
    const float* bout = (const float*)d_in[14];

    char* ws = (char*)d_ws;
    float* mu   = (float*)(ws);                 // 1024 f32
    float* rstd = (float*)(ws + 4096);          // 1024 f32
    float* S1   = (float*)(ws + 8192);          // 4096 f32
    unsigned short* A2 = (unsigned short*)(ws + 32768);              // 1024x4096 bf16
    unsigned short* A3 = (unsigned short*)(ws + 32768 + (8u << 20)); // 1024x4096 bf16
    unsigned short* A4 = A2;                                         // 1024x2048 bf16 (reuse)

    ln_stats_kernel<<<1024, 256, 0, stream>>>(x, mu, rstd);
    rowsum_kernel<<<1024, 256, 0, stream>>>(W1, S1, 2048);

    // layer 1: A = raw f32 x, split-precision GEMM, LN folded into epilogue
    gemm_kan_kernel<0><<<dim3(32, 8), 256, 0, stream>>>(x, W1, b1, cp1, rw1, mu, rstd, S1,
                                                        A2, 1024, 4096, 2048);
    gemm_kan_kernel<1><<<dim3(32, 8), 256, 0, stream>>>(A2, W2, b2, cp2, rw2, nullptr, nullptr, nullptr,
                                                        A3, 1024, 4096, 4096);
    gemm_kan_kernel<1><<<dim3(16, 8), 256, 0, stream>>>(A3, W3, b3, cp3, rw3, nullptr, nullptr, nullptr,
                                                        A4, 1024, 2048, 4096);
    gemm_kan_kernel<2><<<dim3(16, 8), 256, 0, stream>>>(A4, Wout, bout, nullptr, nullptr, nullptr, nullptr, nullptr,
                                                        d_out, 1024, 2048, 2048);
}

// Round 4
// 589.691 us; speedup vs baseline: 1.5382x; 1.5382x over previous
//
#include <hip/hip_runtime.h>

typedef __attribute__((ext_vector_type(8))) short bf16x8;
typedef __attribute__((ext_vector_type(4))) float f32x4;

__device__ __forceinline__ float b2f(unsigned short u) {
    union { unsigned int i; float f; } x; x.i = ((unsigned int)u) << 16; return x.f;
}
__device__ __forceinline__ unsigned short f2b(float f) {
    union { float f; unsigned int i; } x; x.f = f;
    unsigned int r = x.i + 0x7fffu + ((x.i >> 16) & 1u);  // RNE
    return (unsigned short)(r >> 16);
}

// Partial Cox-de Boor exactly as the reference leaves it:
// cols 0-4 degree 3, col 5 degree 2, col 6 degree 1, col 7 degree 0.
// knots = [-1,-1,-1,-1,-0.6,-0.2,0.2,0.6,1,1,1,1]
__device__ __forceinline__ float kan_spline(float t, const float* cpf, float rwf) {
    float c3 = (t >= -1.0f && t < -0.6f) ? 1.0f : 0.0f;
    float c4 = (t >= -0.6f && t < -0.2f) ? 1.0f : 0.0f;
    float c5 = (t >= -0.2f && t <  0.2f) ? 1.0f : 0.0f;
    float c6 = (t >=  0.2f && t <  0.6f) ? 1.0f : 0.0f;
    float c7 = (t >=  0.6f && t <  1.0f) ? 1.0f : 0.0f;
    float d2 = (-0.6f - t) * 2.5f * c3;
    float d3 = (t + 1.0f) * 2.5f * c3 + (-0.2f - t) * 2.5f * c4;
    float d4 = (t + 0.6f) * 2.5f * c4 + ( 0.2f - t) * 2.5f * c5;
    float d5 = (t + 0.2f) * 2.5f * c5 + ( 0.6f - t) * 2.5f * c6;
    float d6 = (t - 0.2f) * 2.5f * c6 + ( 1.0f - t) * 2.5f * c7;
    float e1 = (-0.6f - t) * 2.5f  * d2;
    float e2 = (t + 1.0f) * 2.5f  * d2 + (-0.2f - t) * 1.25f * d3;
    float e3 = (t + 1.0f) * 1.25f * d3 + ( 0.2f - t) * 1.25f * d4;
    float e4 = (t + 0.6f) * 1.25f * d4 + ( 0.6f - t) * 1.25f * d5;
    float e5 = (t + 0.2f) * 1.25f * d5 + ( 1.0f - t) * 1.25f * d6;
    const float r12 = 1.0f / 1.2f;
    float f0 = (-0.6f - t) * 2.5f  * e1;
    float f1 = (t + 1.0f) * 2.5f  * e1 + (-0.2f - t) * 1.25f * e2;
    float f2 = (t + 1.0f) * 1.25f * e2 + ( 0.2f - t) * r12   * e3;
    float f3 = (t + 1.0f) * r12   * e3 + ( 0.6f - t) * r12   * e4;
    float f4 = (t + 0.6f) * r12   * e4 + ( 1.0f - t) * r12   * e5;
    float sp = f0*cpf[0] + f1*cpf[1] + f2*cpf[2] + f3*cpf[3] + f4*cpf[4]
             + e5*cpf[5] + d6*cpf[6] + c7*cpf[7];
    float v = sp * rwf;
    return fminf(fmaxf(v, -10.0f), 10.0f);
}

// per-row mean / rstd of x[1024,2048] f32, fp64 accumulate
__global__ void ln_stats_kernel(const float* __restrict__ x,
                                float* __restrict__ mu, float* __restrict__ rstd) {
    const int row = blockIdx.x;
    const float* p = x + (size_t)row * 2048 + threadIdx.x * 8;
    double s = 0.0, q = 0.0;
#pragma unroll
    for (int i = 0; i < 8; ++i) { float v = p[i]; s += v; q += (double)v * v; }
    for (int o = 32; o > 0; o >>= 1) { s += __shfl_down(s, o, 64); q += __shfl_down(q, o, 64); }
    __shared__ double shs[4], shq[4];
    const int lane = threadIdx.x & 63, w = threadIdx.x >> 6;
    if (lane == 0) { shs[w] = s; shq[w] = q; }
    __syncthreads();
    if (threadIdx.x == 0) {
        double S = shs[0] + shs[1] + shs[2] + shs[3];
        double Q = shq[0] + shq[1] + shq[2] + shq[3];
        double m = S / 2048.0;
        double var = Q / 2048.0 - m * m;
        mu[row] = (float)m;
        rstd[row] = (float)(1.0 / sqrt(var + 1e-5));
    }
}

// S[n] = sum_k W[n,k] (f32 W); one wave per row, 4 rows per block
__global__ void rowsum_kernel(const float* __restrict__ W,
                              float* __restrict__ S, int K) {
    const int lane = threadIdx.x & 63, w = threadIdx.x >> 6;
    const int row = blockIdx.x * 4 + w;
    const float* p = W + (size_t)row * K;
    double s = 0.0;
    for (int c = lane * 8; c < K; c += 512) {
#pragma unroll
        for (int i = 0; i < 8; ++i) s += p[c + i];
    }
    for (int o = 32; o > 0; o >>= 1) s += __shfl_down(s, o, 64);
    if (lane == 0) S[row] = (float)s;
}

// C[M=1024,N] = A[M,K] @ B[N,K]^T with fused epilogue.
// BK=64, LDS rows padded to 72 shorts (144B stride -> <=2-way banks).
// 256 threads, 4 waves in 2x2, wave tile (BM/2)x(BN/2).
// EPI 0: A = f32 x, B = f32 W; staged once per tile into bf16 {hi,lo};
//        acc = Ahi*Bhi + Alo*Bhi + Ahi*Blo (split precision).
//        lin = rstd*(acc - mu*S1) + bias, KAN + NCT, bf16 out.
// EPI 1: A = bf16 act, B = f32 W (staged -> bf16 hi). lin = acc + bias,
//        KAN + NCT, bf16 out.
// EPI 2: like EPI 1 but plain bias epilogue, f32 out.
template <int BM, int BN, int EPI>
__global__ __launch_bounds__(256, 2)
void gemm_kan(const void* __restrict__ Aptr,
              const float* __restrict__ B,
              const float* __restrict__ bias,
              const float* __restrict__ cp,
              const float* __restrict__ rw,
              const float* __restrict__ mu,
              const float* __restrict__ rstd,
              const float* __restrict__ S1,
              void* __restrict__ outp,
              int N, int K, int lda, int ldb)
{
    constexpr int BK = 64;
    constexpr int LDP = 72;                     // padded row stride (shorts)
    constexpr bool SPLIT = (EPI == 0);
    constexpr int WM = BM / 2, WN = BN / 2;
    constexpr int FM = WM / 16, FN = WN / 16;
    constexpr int OFF_B  = BM * LDP;            // lBh after lAh
    constexpr int OFF_LO = (BM + BN) * LDP;     // lo copies after hi block

    __shared__ unsigned short lds[(SPLIT ? 2 : 1) * (BM + BN) * LDP];

    const int tid  = threadIdx.x;
    const int lane = tid & 63;
    const int wid  = tid >> 6;
    const int bm = blockIdx.y * BM;
    const int bn = blockIdx.x * BN;
    const int wmo = (wid >> 1) * WM;
    const int wno = (wid & 1) * WN;
    const int fr = lane & 15;
    const int kq = lane >> 4;

    f32x4 acc[FM][FN] = {};

    for (int k0 = 0; k0 < K; k0 += BK) {
        // ---- stage B (f32 -> bf16), 64 rows per pass, 16 f32 per thread ----
#pragma unroll
        for (int q = 0; q < BN / 64; ++q) {
            const int r = q * 64 + (tid >> 2);
            const int c = (tid & 3) << 4;
            const float* g = B + (size_t)(bn + r) * ldb + k0 + c;
            float v[16];
            *(float4*)&v[0]  = ((const float4*)g)[0];
            *(float4*)&v[4]  = ((const float4*)g)[1];
            *(float4*)&v[8]  = ((const float4*)g)[2];
            *(float4*)&v[12] = ((const float4*)g)[3];
            unsigned short hi[16], lo[16];
#pragma unroll
            for (int i = 0; i < 16; ++i) {
                hi[i] = f2b(v[i]);
                if (SPLIT) lo[i] = f2b(v[i] - b2f(hi[i]));
            }
            unsigned short* d = &lds[OFF_B + r * LDP + c];
            ((uint4*)d)[0] = *(const uint4*)&hi[0];
            ((uint4*)d)[1] = *(const uint4*)&hi[8];
            if (SPLIT) {
                unsigned short* dl = d + OFF_LO;
                ((uint4*)dl)[0] = *(const uint4*)&lo[0];
                ((uint4*)dl)[1] = *(const uint4*)&lo[8];
            }
        }
        // ---- stage A ----
        if constexpr (SPLIT) {
            const int r = tid >> 2;
            const int c = (tid & 3) << 4;
            const float* g = (const float*)Aptr + (size_t)(bm + r) * lda + k0 + c;
            float v[16];
            *(float4*)&v[0]  = ((const float4*)g)[0];
            *(float4*)&v[4]  = ((const float4*)g)[1];
            *(float4*)&v[8]  = ((const float4*)g)[2];
            *(float4*)&v[12] = ((const float4*)g)[3];
            unsigned short hi[16], lo[16];
#pragma unroll
            for (int i = 0; i < 16; ++i) {
                hi[i] = f2b(v[i]);
                lo[i] = f2b(v[i] - b2f(hi[i]));
            }
            unsigned short* d = &lds[r * LDP + c];
            ((uint4*)d)[0] = *(const uint4*)&hi[0];
            ((uint4*)d)[1] = *(const uint4*)&hi[8];
            unsigned short* dl = d + OFF_LO;
            ((uint4*)dl)[0] = *(const uint4*)&lo[0];
            ((uint4*)dl)[1] = *(const uint4*)&lo[8];
        } else {
            const unsigned short* Ab = (const unsigned short*)Aptr;
#pragma unroll
            for (int q = 0; q < 2; ++q) {
                const int r = q * 32 + (tid >> 3);
                const int c = (tid & 7) << 3;
                *(uint4*)&lds[r * LDP + c] =
                    *(const uint4*)(Ab + (size_t)(bm + r) * lda + k0 + c);
            }
        }
        __syncthreads();
        // ---- MFMA ----
#pragma unroll
        for (int s = 0; s < 2; ++s) {
            const int cc = (s * 4 + kq) << 3;   // k-chunk column (shorts)
            bf16x8 aF[FM], bF[FN];
#pragma unroll
            for (int i = 0; i < FM; ++i)
                aF[i] = *(const bf16x8*)&lds[(wmo + i * 16 + fr) * LDP + cc];
#pragma unroll
            for (int j = 0; j < FN; ++j)
                bF[j] = *(const bf16x8*)&lds[OFF_B + (wno + j * 16 + fr) * LDP + cc];
#pragma unroll
            for (int i = 0; i < FM; ++i)
#pragma unroll
                for (int j = 0; j < FN; ++j)
                    acc[i][j] = __builtin_amdgcn_mfma_f32_16x16x32_bf16(aF[i], bF[j], acc[i][j], 0, 0, 0);
            if constexpr (SPLIT) {
                bf16x8 aL[FM], bL[FN];
#pragma unroll
                for (int i = 0; i < FM; ++i)
                    aL[i] = *(const bf16x8*)&lds[OFF_LO + (wmo + i * 16 + fr) * LDP + cc];
#pragma unroll
                for (int i = 0; i < FM; ++i)
#pragma unroll
                    for (int j = 0; j < FN; ++j)
                        acc[i][j] = __builtin_amdgcn_mfma_f32_16x16x32_bf16(aL[i], bF[j], acc[i][j], 0, 0, 0);
#pragma unroll
                for (int j = 0; j < FN; ++j)
                    bL[j] = *(const bf16x8*)&lds[OFF_LO + OFF_B + (wno + j * 16 + fr) * LDP + cc];
#pragma unroll
                for (int i = 0; i < FM; ++i)
#pragma unroll
                    for (int j = 0; j < FN; ++j)
                        acc[i][j] = __builtin_amdgcn_mfma_f32_16x16x32_bf16(aF[i], bL[j], acc[i][j], 0, 0, 0);
            }
        }
        __syncthreads();
    }

    // ---- epilogue: C layout col = lane&15, row = (lane>>4)*4 + reg ----
    const int rowg = (lane >> 4) * 4;
#pragma unroll
    for (int j = 0; j < FN; ++j) {
        const int n = bn + wno + j * 16 + fr;
        const float bs = bias[n];
        float cpf[8], rwf = 0.0f, s1 = 0.0f;
        if (EPI < 2) {
#pragma unroll
            for (int q = 0; q < 8; ++q) cpf[q] = cp[(size_t)n * 9 + q];
            rwf = rw[n];
        }
        if (EPI == 0) s1 = S1[n];
        const int s = n & 7;  // generator slot: {0,1}->sx, {2,3}->sy, {4..7}->identity
#pragma unroll
        for (int i = 0; i < FM; ++i) {
            const int m0 = bm + wmo + i * 16 + rowg;
#pragma unroll
            for (int r = 0; r < 4; ++r) {
                const int m = m0 + r;
                float v = acc[i][j][r];
                if (EPI == 0) v = (v - mu[m] * s1) * rstd[m] + bs;
                else          v += bs;
                if (EPI < 2) {
                    v = kan_spline(tanhf(v), cpf, rwf);
                    float p = __shfl_xor(v, 1, 64);  // partner col n^1 lives in lane^1
                    p = fminf(fmaxf(p, -1.0f), 1.0f);
                    if (s < 4) v += ((s == 2) ? -0.05f : 0.05f) * p;
                }
                if (EPI == 2) ((float*)outp)[(size_t)m * N + n] = v;
                else ((unsigned short*)outp)[(size_t)m * N + n] = f2b(v);
            }
        }
    }
}

extern "C" void kernel_launch(void* const* d_in, const int* in_sizes, int n_in,
                              void* d_out, int out_size, void* d_ws, size_t ws_size,
                              hipStream_t stream) {
    const float* x    = (const float*)d_in[0];
    const float* W1   = (const float*)d_in[1];
    const float* b1   = (const float*)d_in[2];
    const float* cp1  = (const float*)d_in[3];
    const float* rw1  = (const float*)d_in[4];
    const float* W2   = (const float*)d_in[5];
    const float* b2   = (const float*)d_in[6];
    const float* cp2  = (const float*)d_in[7];
    const float* rw2  = (const float*)d_in[8];
    const float* W3   = (const float*)d_in[9];
    const float* b3   = (const float*)d_in[10];
    const float* cp3  = (const float*)d_in[11];
    const float* rw3  = (const float*)d_in[12];
    const float* Wout = (const float*)d_in[13];
    const float* bout = (const float*)d_in[14];

    // ws footprint: 32KB + 8MB + 8MB = 16.81 MB (== round-2-proven peak)
    char* ws = (char*)d_ws;
    float* mu   = (float*)(ws);                  // 1024 f32
    float* rstd = (float*)(ws + 4096);           // 1024 f32
    float* S1   = (float*)(ws + 8192);           // 4096 f32
    unsigned short* A2 = (unsigned short*)(ws + 32768);              // 1024x4096 bf16
    unsigned short* A3 = (unsigned short*)(ws + 32768 + 8388608);    // 1024x4096 bf16
    unsigned short* A4 = A2;                     // 1024x2048 bf16 (A2 dead after L2)

    ln_stats_kernel<<<1024, 256, 0, stream>>>(x, mu, rstd);
    rowsum_kernel<<<1024, 256, 0, stream>>>(W1, S1, 2048);

    // layer 1: split-precision (single-fetch, 3 MFMA groups), LN folded
    gemm_kan<64, 128, 0><<<dim3(32, 16), 256, 0, stream>>>(
        x, W1, b1, cp1, rw1, mu, rstd, S1, A2, 4096, 2048, 2048, 2048);
    // layer 2
    gemm_kan<64, 128, 1><<<dim3(32, 16), 256, 0, stream>>>(
        A2, W2, b2, cp2, rw2, nullptr, nullptr, nullptr, A3, 4096, 4096, 4096, 4096);
    // layer 3
    gemm_kan<64, 64, 1><<<dim3(32, 16), 256, 0, stream>>>(
        A3, W3, b3, cp3, rw3, nullptr, nullptr, nullptr, A4, 2048, 4096, 4096, 4096);
    // output layer
    gemm_kan<64, 64, 2><<<dim3(32, 16), 256, 0, stream>>>(
        A4, Wout, bout, nullptr, nullptr, nullptr, nullptr, nullptr, d_out, 2048, 2048, 2048, 2048);
}

// Round 5
// 568.371 us; speedup vs baseline: 1.5959x; 1.0375x over previous
//
#include <hip/hip_runtime.h>

typedef __attribute__((ext_vector_type(8))) short bf16x8;
typedef __attribute__((ext_vector_type(4))) float f32x4;

__device__ __forceinline__ float b2f(unsigned short u) {
    union { unsigned int i; float f; } x; x.i = ((unsigned int)u) << 16; return x.f;
}
__device__ __forceinline__ unsigned short f2b(float f) {
    union { float f; unsigned int i; } x; x.f = f;
    unsigned int r = x.i + 0x7fffu + ((x.i >> 16) & 1u);  // RNE
    return (unsigned short)(r >> 16);
}

// Partial Cox-de Boor exactly as the reference leaves it:
// cols 0-4 degree 3, col 5 degree 2, col 6 degree 1, col 7 degree 0.
// knots = [-1,-1,-1,-1,-0.6,-0.2,0.2,0.6,1,1,1,1]
__device__ __forceinline__ float kan_spline(float t, const float* cpf, float rwf) {
    float c3 = (t >= -1.0f && t < -0.6f) ? 1.0f : 0.0f;
    float c4 = (t >= -0.6f && t < -0.2f) ? 1.0f : 0.0f;
    float c5 = (t >= -0.2f && t <  0.2f) ? 1.0f : 0.0f;
    float c6 = (t >=  0.2f && t <  0.6f) ? 1.0f : 0.0f;
    float c7 = (t >=  0.6f && t <  1.0f) ? 1.0f : 0.0f;
    float d2 = (-0.6f - t) * 2.5f * c3;
    float d3 = (t + 1.0f) * 2.5f * c3 + (-0.2f - t) * 2.5f * c4;
    float d4 = (t + 0.6f) * 2.5f * c4 + ( 0.2f - t) * 2.5f * c5;
    float d5 = (t + 0.2f) * 2.5f * c5 + ( 0.6f - t) * 2.5f * c6;
    float d6 = (t - 0.2f) * 2.5f * c6 + ( 1.0f - t) * 2.5f * c7;
    float e1 = (-0.6f - t) * 2.5f  * d2;
    float e2 = (t + 1.0f) * 2.5f  * d2 + (-0.2f - t) * 1.25f * d3;
    float e3 = (t + 1.0f) * 1.25f * d3 + ( 0.2f - t) * 1.25f * d4;
    float e4 = (t + 0.6f) * 1.25f * d4 + ( 0.6f - t) * 1.25f * d5;
    float e5 = (t + 0.2f) * 1.25f * d5 + ( 1.0f - t) * 1.25f * d6;
    const float r12 = 1.0f / 1.2f;
    float f0 = (-0.6f - t) * 2.5f  * e1;
    float f1 = (t + 1.0f) * 2.5f  * e1 + (-0.2f - t) * 1.25f * e2;
    float f2 = (t + 1.0f) * 1.25f * e2 + ( 0.2f - t) * r12   * e3;
    float f3 = (t + 1.0f) * r12   * e3 + ( 0.6f - t) * r12   * e4;
    float f4 = (t + 0.6f) * r12   * e4 + ( 1.0f - t) * r12   * e5;
    float sp = f0*cpf[0] + f1*cpf[1] + f2*cpf[2] + f3*cpf[3] + f4*cpf[4]
             + e5*cpf[5] + d6*cpf[6] + c7*cpf[7];
    float v = sp * rwf;
    return fminf(fmaxf(v, -10.0f), 10.0f);
}

// per-row mean / rstd of x[1024,2048] f32, fp64 accumulate
__global__ void ln_stats_kernel(const float* __restrict__ x,
                                float* __restrict__ mu, float* __restrict__ rstd) {
    const int row = blockIdx.x;
    const float* p = x + (size_t)row * 2048 + threadIdx.x * 8;
    double s = 0.0, q = 0.0;
#pragma unroll
    for (int i = 0; i < 8; ++i) { float v = p[i]; s += v; q += (double)v * v; }
    for (int o = 32; o > 0; o >>= 1) { s += __shfl_down(s, o, 64); q += __shfl_down(q, o, 64); }
    __shared__ double shs[4], shq[4];
    const int lane = threadIdx.x & 63, w = threadIdx.x >> 6;
    if (lane == 0) { shs[w] = s; shq[w] = q; }
    __syncthreads();
    if (threadIdx.x == 0) {
        double S = shs[0] + shs[1] + shs[2] + shs[3];
        double Q = shq[0] + shq[1] + shq[2] + shq[3];
        double m = S / 2048.0;
        double var = Q / 2048.0 - m * m;
        mu[row] = (float)m;
        rstd[row] = (float)(1.0 / sqrt(var + 1e-5));
    }
}

// S[n] = sum_k W[n,k] (f32 W); one wave per row, 4 rows per block
__global__ void rowsum_kernel(const float* __restrict__ W,
                              float* __restrict__ S, int K) {
    const int lane = threadIdx.x & 63, w = threadIdx.x >> 6;
    const int row = blockIdx.x * 4 + w;
    const float* p = W + (size_t)row * K;
    double s = 0.0;
    for (int c = lane * 8; c < K; c += 512) {
#pragma unroll
        for (int i = 0; i < 8; ++i) s += p[c + i];
    }
    for (int o = 32; o > 0; o >>= 1) s += __shfl_down(s, o, 64);
    if (lane == 0) S[row] = (float)s;
}

// C[M=1024,N] = A[M,K] @ B[N,K]^T with fused epilogue. Software-pipelined:
// tile k+1 is prefetched into registers while MFMA runs on tile k.
// BK=64, LDS rows padded to 72 shorts (144B stride).
// 256 threads, 4 waves in 2x2, wave tile (BM/2)x(BN/2).
// EPI 0: A = f32 x, B = f32 W; staged once per tile into bf16 {hi,lo};
//        acc = Ahi*Bhi + Alo*Bhi + Ahi*Blo (split precision).
//        lin = rstd*(acc - mu*S1) + bias, KAN + NCT, bf16 out.
// EPI 1: A = bf16 act, B = f32 W (staged -> bf16 hi). lin = acc + bias,
//        KAN + NCT, bf16 out.
// EPI 2: like EPI 1 but plain bias epilogue, f32 out.
template <int BM, int BN, int EPI>
__global__ __launch_bounds__(256, 2)
void gemm_kan(const void* __restrict__ Aptr,
              const float* __restrict__ B,
              const float* __restrict__ bias,
              const float* __restrict__ cp,
              const float* __restrict__ rw,
              const float* __restrict__ mu,
              const float* __restrict__ rstd,
              const float* __restrict__ S1,
              void* __restrict__ outp,
              int N, int K, int lda, int ldb)
{
    constexpr int BK = 64;
    constexpr int LDP = 72;                     // padded row stride (shorts)
    constexpr bool SPLIT = (EPI == 0);
    constexpr int WM = BM / 2, WN = BN / 2;
    constexpr int FM = WM / 16, FN = WN / 16;
    constexpr int OFF_B  = BM * LDP;            // lB after lA
    constexpr int OFF_LO = (BM + BN) * LDP;     // lo copies after hi block
    constexpr int NBQ = BN / 64;

    __shared__ unsigned short lds[(SPLIT ? 2 : 1) * (BM + BN) * LDP];

    const int tid  = threadIdx.x;
    const int lane = tid & 63;
    const int wid  = tid >> 6;
    const int bm = blockIdx.y * BM;
    const int bn = blockIdx.x * BN;
    const int wmo = (wid >> 1) * WM;
    const int wno = (wid & 1) * WN;
    const int fr = lane & 15;
    const int kq = lane >> 4;

    // staging coords
    const int sbr = tid >> 2;          // row within 64-row staging pass
    const int sbc = (tid & 3) << 4;    // f32 col (16 per thread)
    const int sar = tid >> 3;          // bf16 A row (0..31)
    const int sac = (tid & 7) << 3;    // bf16 A col (8 shorts)

    float rB[NBQ][16];                 // prefetch registers
    float rA[16];
    uint4 rAb[2];

    auto load_tiles = [&](int k) {
#pragma unroll
        for (int q = 0; q < NBQ; ++q) {
            const float* g = B + (size_t)(bn + q * 64 + sbr) * ldb + k + sbc;
            *(float4*)&rB[q][0]  = ((const float4*)g)[0];
            *(float4*)&rB[q][4]  = ((const float4*)g)[1];
            *(float4*)&rB[q][8]  = ((const float4*)g)[2];
            *(float4*)&rB[q][12] = ((const float4*)g)[3];
        }
        if constexpr (SPLIT) {
            const float* g = (const float*)Aptr + (size_t)(bm + sbr) * lda + k + sbc;
            *(float4*)&rA[0]  = ((const float4*)g)[0];
            *(float4*)&rA[4]  = ((const float4*)g)[1];
            *(float4*)&rA[8]  = ((const float4*)g)[2];
            *(float4*)&rA[12] = ((const float4*)g)[3];
        } else {
            const unsigned short* Ab = (const unsigned short*)Aptr;
            rAb[0] = *(const uint4*)(Ab + (size_t)(bm + sar) * lda + k + sac);
            rAb[1] = *(const uint4*)(Ab + (size_t)(bm + 32 + sar) * lda + k + sac);
        }
    };

    auto stage_lds = [&]() {
#pragma unroll
        for (int q = 0; q < NBQ; ++q) {
            unsigned short hi[16], lo[16];
#pragma unroll
            for (int i = 0; i < 16; ++i) {
                hi[i] = f2b(rB[q][i]);
                if (SPLIT) lo[i] = f2b(rB[q][i] - b2f(hi[i]));
            }
            unsigned short* d = &lds[OFF_B + (q * 64 + sbr) * LDP + sbc];
            ((uint4*)d)[0] = *(const uint4*)&hi[0];
            ((uint4*)d)[1] = *(const uint4*)&hi[8];
            if (SPLIT) {
                unsigned short* dl = d + OFF_LO;
                ((uint4*)dl)[0] = *(const uint4*)&lo[0];
                ((uint4*)dl)[1] = *(const uint4*)&lo[8];
            }
        }
        if constexpr (SPLIT) {
            unsigned short hi[16], lo[16];
#pragma unroll
            for (int i = 0; i < 16; ++i) {
                hi[i] = f2b(rA[i]);
                lo[i] = f2b(rA[i] - b2f(hi[i]));
            }
            unsigned short* d = &lds[sbr * LDP + sbc];
            ((uint4*)d)[0] = *(const uint4*)&hi[0];
            ((uint4*)d)[1] = *(const uint4*)&hi[8];
            unsigned short* dl = d + OFF_LO;
            ((uint4*)dl)[0] = *(const uint4*)&lo[0];
            ((uint4*)dl)[1] = *(const uint4*)&lo[8];
        } else {
            *(uint4*)&lds[sar * LDP + sac] = rAb[0];
            *(uint4*)&lds[(32 + sar) * LDP + sac] = rAb[1];
        }
    };

    f32x4 acc[FM][FN] = {};

    load_tiles(0);
    for (int k0 = 0; k0 < K; k0 += BK) {
        stage_lds();                            // consumes prefetch regs (vmcnt wait here)
        __syncthreads();
        if (k0 + BK < K) load_tiles(k0 + BK);   // in flight across the MFMA section
        // ---- MFMA ----
#pragma unroll
        for (int s = 0; s < 2; ++s) {
            const int cc = (s * 4 + kq) << 3;   // k-chunk column (shorts)
            bf16x8 aF[FM], bF[FN];
#pragma unroll
            for (int i = 0; i < FM; ++i)
                aF[i] = *(const bf16x8*)&lds[(wmo + i * 16 + fr) * LDP + cc];
#pragma unroll
            for (int j = 0; j < FN; ++j)
                bF[j] = *(const bf16x8*)&lds[OFF_B + (wno + j * 16 + fr) * LDP + cc];
#pragma unroll
            for (int i = 0; i < FM; ++i)
#pragma unroll
                for (int j = 0; j < FN; ++j)
                    acc[i][j] = __builtin_amdgcn_mfma_f32_16x16x32_bf16(aF[i], bF[j], acc[i][j], 0, 0, 0);
            if constexpr (SPLIT) {
                bf16x8 aL[FM], bL[FN];
#pragma unroll
                for (int i = 0; i < FM; ++i)
                    aL[i] = *(const bf16x8*)&lds[OFF_LO + (wmo + i * 16 + fr) * LDP + cc];
#pragma unroll
                for (int i = 0; i < FM; ++i)
#pragma unroll
                    for (int j = 0; j < FN; ++j)
                        acc[i][j] = __builtin_amdgcn_mfma_f32_16x16x32_bf16(aL[i], bF[j], acc[i][j], 0, 0, 0);
#pragma unroll
                for (int j = 0; j < FN; ++j)
                    bL[j] = *(const bf16x8*)&lds[OFF_LO + OFF_B + (wno + j * 16 + fr) * LDP + cc];
#pragma unroll
                for (int i = 0; i < FM; ++i)
#pragma unroll
                    for (int j = 0; j < FN; ++j)
                        acc[i][j] = __builtin_amdgcn_mfma_f32_16x16x32_bf16(aF[i], bL[j], acc[i][j], 0, 0, 0);
            }
        }
        __syncthreads();
    }

    // ---- epilogue: C layout col = lane&15, row = (lane>>4)*4 + reg ----
    const int rowg = (lane >> 4) * 4;
#pragma unroll
    for (int j = 0; j < FN; ++j) {
        const int n = bn + wno + j * 16 + fr;
        const float bs = bias[n];
        float cpf[8], rwf = 0.0f, s1 = 0.0f;
        if (EPI < 2) {
#pragma unroll
            for (int q = 0; q < 8; ++q) cpf[q] = cp[(size_t)n * 9 + q];
            rwf = rw[n];
        }
        if (EPI == 0) s1 = S1[n];
        const int s = n & 7;  // generator slot: {0,1}->sx, {2,3}->sy, {4..7}->identity
#pragma unroll
        for (int i = 0; i < FM; ++i) {
            const int m0 = bm + wmo + i * 16 + rowg;
#pragma unroll
            for (int r = 0; r < 4; ++r) {
                const int m = m0 + r;
                float v = acc[i][j][r];
                if (EPI == 0) v = (v - mu[m] * s1) * rstd[m] + bs;
                else          v += bs;
                if (EPI < 2) {
                    v = kan_spline(tanhf(v), cpf, rwf);
                    float p = __shfl_xor(v, 1, 64);  // partner col n^1 lives in lane^1
                    p = fminf(fmaxf(p, -1.0f), 1.0f);
                    if (s < 4) v += ((s == 2) ? -0.05f : 0.05f) * p;
                }
                if (EPI == 2) ((float*)outp)[(size_t)m * N + n] = v;
                else ((unsigned short*)outp)[(size_t)m * N + n] = f2b(v);
            }
        }
    }
}

extern "C" void kernel_launch(void* const* d_in, const int* in_sizes, int n_in,
                              void* d_out, int out_size, void* d_ws, size_t ws_size,
                              hipStream_t stream) {
    const float* x    = (const float*)d_in[0];
    const float* W1   = (const float*)d_in[1];
    const float* b1   = (const float*)d_in[2];
    const float* cp1  = (const float*)d_in[3];
    const float* rw1  = (const float*)d_in[4];
    const float* W2   = (const float*)d_in[5];
    const float* b2   = (const float*)d_in[6];
    const float* cp2  = (const float*)d_in[7];
    const float* rw2  = (const float*)d_in[8];
    const float* W3   = (const float*)d_in[9];
    const float* b3   = (const float*)d_in[10];
    const float* cp3  = (const float*)d_in[11];
    const float* rw3  = (const float*)d_in[12];
    const float* Wout = (const float*)d_in[13];
    const float* bout = (const float*)d_in[14];

    // ws footprint: 32KB + 8MB + 8MB = 16.81 MB (round-2-proven size)
    char* ws = (char*)d_ws;
    float* mu   = (float*)(ws);                  // 1024 f32
    float* rstd = (float*)(ws + 4096);           // 1024 f32
    float* S1   = (float*)(ws + 8192);           // 4096 f32
    unsigned short* A2 = (unsigned short*)(ws + 32768);              // 1024x4096 bf16
    unsigned short* A3 = (unsigned short*)(ws + 32768 + 8388608);    // 1024x4096 bf16
    unsigned short* A4 = A2;                     // 1024x2048 bf16 (A2 dead after L2)

    ln_stats_kernel<<<1024, 256, 0, stream>>>(x, mu, rstd);
    rowsum_kernel<<<1024, 256, 0, stream>>>(W1, S1, 2048);

    // layer 1: split-precision (single-fetch, 3 MFMA groups), LN folded
    gemm_kan<64, 128, 0><<<dim3(32, 16), 256, 0, stream>>>(
        x, W1, b1, cp1, rw1, mu, rstd, S1, A2, 4096, 2048, 2048, 2048);
    // layer 2
    gemm_kan<64, 128, 1><<<dim3(32, 16), 256, 0, stream>>>(
        A2, W2, b2, cp2, rw2, nullptr, nullptr, nullptr, A3, 4096, 4096, 4096, 4096);
    // layer 3
    gemm_kan<64, 64, 1><<<dim3(32, 16), 256, 0, stream>>>(
        A3, W3, b3, cp3, rw3, nullptr, nullptr, nullptr, A4, 2048, 4096, 4096, 4096);
    // output layer
    gemm_kan<64, 64, 2><<<dim3(32, 16), 256, 0, stream>>>(
        A4, Wout, bout, nullptr, nullptr, nullptr, nullptr, nullptr, d_out, 2048, 2048, 2048, 2048);
}